// Round 16
// baseline (227.395 us; speedup 1.0000x reference)
//
#include <hip/hip_runtime.h>

typedef unsigned short u16;
typedef unsigned int u32;
typedef __attribute__((ext_vector_type(8))) short short8;
typedef __attribute__((ext_vector_type(4))) float f32x4;
typedef __attribute__((ext_vector_type(16))) float f32x16;
typedef __attribute__((ext_vector_type(4))) u16 u16x4;
typedef __attribute__((ext_vector_type(4))) u32 u32x4;

#define QK_SCALE 0.12751736915185197f  // log2(e)/sqrt(128)

__device__ __forceinline__ u16 f2bf(float f) {
  u32 u = __builtin_bit_cast(u32, f);
  u = u + 0x7FFFu + ((u >> 16) & 1u);
  return (u16)(u >> 16);
}

__device__ __forceinline__ void async_copy16(const void* g, void* l) {
  __builtin_amdgcn_global_load_lds(
      (const __attribute__((address_space(1))) u32*)g,
      (__attribute__((address_space(3))) u32*)l, 16, 0, 0);
}

#define VMCNT(n) asm volatile("s_waitcnt vmcnt(" #n ")" ::: "memory")

// ---------------- cast x (fp32 -> bf16) ----------------
__global__ __launch_bounds__(256) void cast_x_kernel(const float* __restrict__ x,
                                                     u16* __restrict__ xb, int n) {
  int i = (blockIdx.x * 256 + threadIdx.x) * 8;
  if (i >= n) return;
  float4 a = *(const float4*)(x + i);
  float4 b = *(const float4*)(x + i + 4);
  short8 o;
  o[0] = (short)f2bf(a.x); o[1] = (short)f2bf(a.y);
  o[2] = (short)f2bf(a.z); o[3] = (short)f2bf(a.w);
  o[4] = (short)f2bf(b.x); o[5] = (short)f2bf(b.y);
  o[6] = (short)f2bf(b.z); o[7] = (short)f2bf(b.w);
  *(short8*)(xb + i) = o;
}

// ---------------- transpose+cast W (fp32 [k][n] -> bf16 WT [n][k]) ----------------
__global__ __launch_bounds__(256) void transW_kernel(
    const float* __restrict__ W0, const float* __restrict__ W1,
    const float* __restrict__ W2, const float* __restrict__ W3,
    u16* __restrict__ O0, u16* __restrict__ O1, u16* __restrict__ O2, u16* __restrict__ O3) {
  const float* Ws[4] = {W0, W1, W2, W3};
  u16* Os[4] = {O0, O1, O2, O3};
  const float* W = Ws[blockIdx.z];
  u16* O = Os[blockIdx.z];

  __shared__ float T[64][65];
  int t = threadIdx.x;
  int k0 = blockIdx.y * 64, n0 = blockIdx.x * 64;
  int r = t >> 4, c = (t & 15) * 4;
#pragma unroll
  for (int i = 0; i < 4; ++i) {
    float4 v = *(const float4*)&W[(size_t)(k0 + r + i * 16) * 2048 + n0 + c];
    T[r + i * 16][c + 0] = v.x; T[r + i * 16][c + 1] = v.y;
    T[r + i * 16][c + 2] = v.z; T[r + i * 16][c + 3] = v.w;
  }
  __syncthreads();
#pragma unroll
  for (int i = 0; i < 4; ++i) {
    int nn = r + i * 16;
    u16x4 o;
    o[0] = f2bf(T[c + 0][nn]); o[1] = f2bf(T[c + 1][nn]);
    o[2] = f2bf(T[c + 2][nn]); o[3] = f2bf(T[c + 3][nn]);
    *(u16x4*)&O[(size_t)(n0 + nn) * 2048 + k0 + c] = o;
  }
}

// ============ 256x192 8-phase GEMM (QKV): BK=64, 8 waves 2Mx4N ==========
// Round-16: restore the true two-barrier 8-phase template (m201 structure):
// per phase {ds_reads | stage} -> barrier -> lgkmcnt(0) -> 12 MFMA -> [vmcnt(5)]
// -> barrier. Stage ladder + vmcnt placement identical to the r9-verified one.
__global__ __launch_bounds__(512, 2) void gemm192_kernel(
    const u16* __restrict__ A, const u16* __restrict__ W,
    const float* __restrict__ b0, const float* __restrict__ b1, const float* __restrict__ b2,
    u16* __restrict__ oq, u16* __restrict__ ok, u16* __restrict__ ovt) {
  __shared__ __align__(16) u16 SM[57344];  // 112 KB

  int t = threadIdx.x;
  int lane = t & 63, w = t >> 6;
  int wm = w >> 2, wn = w & 3;
  int g = lane >> 4, lr = lane & 15;
  int m0 = blockIdx.y * 256, n0 = blockIdx.x * 192;

  const u16* AsrcB = A + (size_t)(m0 + (t >> 3)) * 2048 + ((t & 7) ^ ((t >> 3) & 7)) * 8;
  const u16* BsrcB = W + (size_t)(n0 + (t >> 3)) * 2048 + ((t & 7) ^ ((t >> 3) & 7)) * 8;
  int t8 = t * 8;

  int ko0 = (g ^ (lr & 7)) * 8;
  int ko1 = ((4 + g) ^ (lr & 7)) * 8;
  int aoff[8], boff[3];
#pragma unroll
  for (int mf = 0; mf < 8; ++mf) aoff[mf] = (wm * 128 + mf * 16 + lr) * 64;
#pragma unroll
  for (int nf = 0; nf < 3; ++nf) boff[nf] = 16384 + (wn * 48 + nf * 16 + lr) * 64;

  f32x4 acc[8][3] = {};
  short8 bfr[3][2];

#define SA(bb, j, tl) \
  async_copy16(AsrcB + (size_t)(j) * 131072 + (tl) * 64, (void*)(SM + (bb) * 28672 + (j) * 4096 + t8))
#define SB(bb, j, tl) \
  async_copy16(BsrcB + (size_t)(j) * 131072 + (tl) * 64, \
               (void*)(SM + (bb) * 28672 + 16384 + (j) * 4096 + t8))

#define PHASE(hbuf, q, STAGE_OPS, VM_OP)                                        \
  {                                                                             \
    const u16* Ab = SM + (hbuf) * 28672;                                        \
    short8 af[2][2];                                                            \
    af[0][0] = *(const short8*)&Ab[aoff[2 * (q)] + ko0];                        \
    af[0][1] = *(const short8*)&Ab[aoff[2 * (q)] + ko1];                        \
    af[1][0] = *(const short8*)&Ab[aoff[2 * (q) + 1] + ko0];                    \
    af[1][1] = *(const short8*)&Ab[aoff[2 * (q) + 1] + ko1];                    \
    if ((q) == 0) {                                                             \
      _Pragma("unroll") for (int nf = 0; nf < 3; ++nf) {                        \
        bfr[nf][0] = *(const short8*)&Ab[boff[nf] + ko0];                       \
        bfr[nf][1] = *(const short8*)&Ab[boff[nf] + ko1];                       \
      }                                                                         \
    }                                                                           \
    STAGE_OPS;                                                                  \
    __builtin_amdgcn_s_barrier();                                               \
    asm volatile("s_waitcnt lgkmcnt(0)" ::: "memory");                          \
    __builtin_amdgcn_sched_barrier(0);                                          \
    __builtin_amdgcn_s_setprio(1);                                              \
    _Pragma("unroll") for (int kk = 0; kk < 2; ++kk)                            \
        _Pragma("unroll") for (int m2 = 0; m2 < 2; ++m2)                        \
            _Pragma("unroll") for (int nf = 0; nf < 3; ++nf)                    \
                acc[2 * (q) + m2][nf] = __builtin_amdgcn_mfma_f32_16x16x32_bf16(\
                    af[m2][kk], bfr[nf][kk], acc[2 * (q) + m2][nf], 0, 0, 0);   \
    __builtin_amdgcn_s_setprio(0);                                              \
    VM_OP;                                                                      \
    __builtin_amdgcn_s_barrier();                                               \
  }

  // ---- prologue: t0 full (7 sets) -> buf0; t1 partial (5 sets) -> buf1 ----
  SB(0, 0, 0); SB(0, 1, 0); SB(0, 2, 0);
  SA(0, 0, 0); SA(0, 1, 0); SA(0, 2, 0); SA(0, 3, 0);
  SB(1, 0, 1); SB(1, 1, 1); SB(1, 2, 1);
  SA(1, 0, 1); SA(1, 2, 1);
  VMCNT(5);
  __builtin_amdgcn_s_barrier();

  for (int i = 0; i < 16; ++i) {
    bool more = i < 15;
    int t1 = 2 * i + 1, t2 = 2 * i + 2, t3 = 2 * i + 3;
    PHASE(0, 0, { SA(1, 1, t1); SA(1, 3, t1); }, {});
    PHASE(0, 1, { if (more) { SB(0, 0, t2); SB(0, 1, t2); } }, {});
    PHASE(0, 2, { if (more) { SB(0, 2, t2); SA(0, 0, t2); } }, {});
    PHASE(0, 3, { if (more) { SA(0, 2, t2); } },
          { if (more) { VMCNT(5); } else { VMCNT(0); } });
    PHASE(1, 0, { if (more) { SA(0, 1, t2); SA(0, 3, t2); } }, {});
    PHASE(1, 1, { if (more) { SB(1, 0, t3); SB(1, 1, t3); } }, {});
    PHASE(1, 2, { if (more) { SB(1, 2, t3); SA(1, 0, t3); } }, {});
    PHASE(1, 3, { if (more) { SA(1, 2, t3); } },
          { if (more) { VMCNT(5); } else { VMCNT(0); } });
  }
#undef PHASE
#undef SA
#undef SB

  // ---- epilogue: Q/K direct scatter; V cols -> LDS transpose -> coalesced ----
  bool hasV = (n0 + 191) >= 4096;
#pragma unroll
  for (int mf = 0; mf < 8; ++mf) {
#pragma unroll
    for (int nf = 0; nf < 3; ++nf) {
      int colc = wn * 48 + nf * 16 + lr;
      int col = n0 + colc;
      int z = col >> 11;
      int cc = col & 2047;
      if (z < 2) {
        float bv = (z == 0 ? b0 : b1)[cc];
        u16* outb = (z == 0) ? oq : ok;
#pragma unroll
        for (int i = 0; i < 4; ++i) {
          int rr = m0 + wm * 128 + mf * 16 + 4 * g + i;
          int b = rr >> 11, np = rr & 2047, h = cc >> 7, dk = cc & 127;
          outb[((size_t)(b * 16 + h) * 2048 + np) * 128 + dk] = f2bf(acc[mf][nf][i] + bv);
        }
      } else {
        float bv = b2[cc];
#pragma unroll
        for (int i = 0; i < 4; ++i) {
          int token = wm * 128 + mf * 16 + 4 * g + i;
          SM[colc * 264 + token] = f2bf(acc[mf][nf][i] + bv);
        }
      }
    }
  }
  if (hasV) {
    __syncthreads();
    int b = m0 >> 11;
    int npb = m0 & 2047;
#pragma unroll
    for (int it = 0; it < 12; ++it) {
      int id = t + 512 * it;
      int colc = id >> 5;
      int c8 = (id & 31) * 8;
      int col = n0 + colc;
      if (col >= 4096) {
        short8 v = *(const short8*)&SM[colc * 264 + c8];
        int vcol = col - 4096;
        int h = vcol >> 7, dk = vcol & 127;
        *(short8*)&ovt[(((size_t)(b * 16 + h) * 128 + dk) * 2048) + npb + c8] = v;
      }
    }
  }
}

// ---------------- O-proj GEMM: BM=128, BN=256, triple-buffered ----------------
__global__ __launch_bounds__(512, 2) void gemmO_kernel(
    const u16* __restrict__ A, const u16* __restrict__ W,
    const float* __restrict__ bias, float* __restrict__ of) {
  __shared__ __align__(16) u16 SM[73728];  // 144 KB

  int t = threadIdx.x;
  int lane = t & 63, w = t >> 6;
  int wm = w >> 2, wn = w & 3;
  int g = lane >> 4, lr = lane & 15;
  int m0 = blockIdx.y * 128, n0 = blockIdx.x * 256;

  int sArow = ((t >> 8) << 6) + ((t >> 3) & 31);
  int c8A = (t & 7) ^ ((t >> 3) & 7);
  const u16* Asrc = A + (size_t)(m0 + sArow) * 2048 + c8A * 8;
  int rB = t >> 3;
  int c8B = (t & 7) ^ (rB & 7);
  const u16* Bsrc = W + (size_t)(n0 + rB) * 2048 + c8B * 8;

  int ko0 = (g ^ (lr & 7)) * 8;
  int ko1 = ((4 + g) ^ (lr & 7)) * 8;
  int offA[4], offB[4];
#pragma unroll
  for (int mf = 0; mf < 4; ++mf)
    offA[mf] = (mf >> 1) * 4096 + wm * 2048 + ((mf & 1) * 16 + lr) * 64;
#pragma unroll
  for (int nf = 0; nf < 4; ++nf)
    offB[nf] = 8192 + (wn >> 1) * 8192 + ((wn & 1) * 64 + nf * 16 + lr) * 64;

  f32x4 acc[4][4] = {};

#define STG_A(sbuf, mh, kt) \
  async_copy16(Asrc + (mh) * 65536 + (kt), (void*)(SM + (sbuf) + (mh) * 4096 + t * 8))
#define STG_B(sbuf, half, kt)                                                 \
  do {                                                                        \
    async_copy16(Bsrc + (half) * 262144 + (kt),                               \
                 (void*)(SM + (sbuf) + 8192 + (half) * 8192 + t * 8));        \
    async_copy16(Bsrc + (half) * 262144 + 131072 + (kt),                      \
                 (void*)(SM + (sbuf) + 8192 + (half) * 8192 + 4096 + t * 8)); \
  } while (0)

  STG_A(0, 0, 0); STG_B(0, 0, 0);
  STG_A(0, 1, 0); STG_B(0, 1, 0);
  STG_A(24576, 0, 64); STG_B(24576, 0, 64);
  STG_A(24576, 1, 64); STG_B(24576, 1, 64);
  VMCNT(6);
  __builtin_amdgcn_s_barrier();

  u32 cb = 0, sb = 49152;
  for (int tt = 0; tt < 32; ++tt) {
    int kt2 = (tt + 2) << 6;
    bool stg = tt < 30;
    const u16* Bu = SM + cb;

    short8 af[2][2], bfr[4][2];
#pragma unroll
    for (int m2 = 0; m2 < 2; ++m2) {
      af[m2][0] = *(const short8*)&Bu[offA[m2] + ko0];
      af[m2][1] = *(const short8*)&Bu[offA[m2] + ko1];
    }
#pragma unroll
    for (int nf = 0; nf < 4; ++nf) {
      bfr[nf][0] = *(const short8*)&Bu[offB[nf] + ko0];
      bfr[nf][1] = *(const short8*)&Bu[offB[nf] + ko1];
    }
    if (stg) { STG_A(sb, 0, kt2); STG_B(sb, 0, kt2); }
    __builtin_amdgcn_s_barrier();
    __builtin_amdgcn_s_setprio(1);
#pragma unroll
    for (int kk = 0; kk < 2; ++kk)
#pragma unroll
      for (int m2 = 0; m2 < 2; ++m2)
#pragma unroll
        for (int nf = 0; nf < 4; ++nf)
          acc[m2][nf] =
              __builtin_amdgcn_mfma_f32_16x16x32_bf16(af[m2][kk], bfr[nf][kk], acc[m2][nf], 0, 0, 0);
    __builtin_amdgcn_s_setprio(0);
    __builtin_amdgcn_s_barrier();

#pragma unroll
    for (int m2 = 0; m2 < 2; ++m2) {
      af[m2][0] = *(const short8*)&Bu[offA[2 + m2] + ko0];
      af[m2][1] = *(const short8*)&Bu[offA[2 + m2] + ko1];
    }
    if (stg) { STG_A(sb, 1, kt2); STG_B(sb, 1, kt2); }
    __builtin_amdgcn_s_barrier();
    __builtin_amdgcn_s_setprio(1);
#pragma unroll
    for (int kk = 0; kk < 2; ++kk)
#pragma unroll
      for (int m2 = 0; m2 < 2; ++m2)
#pragma unroll
        for (int nf = 0; nf < 4; ++nf)
          acc[2 + m2][nf] = __builtin_amdgcn_mfma_f32_16x16x32_bf16(af[m2][kk], bfr[nf][kk],
                                                                    acc[2 + m2][nf], 0, 0, 0);
    __builtin_amdgcn_s_setprio(0);
    if (tt < 30) { VMCNT(6); } else { VMCNT(0); }
    __builtin_amdgcn_s_barrier();

    cb += 24576; if (cb == 73728) cb = 0;
    sb += 24576; if (sb == 73728) sb = 0;
  }
#undef STG_A
#undef STG_B

#pragma unroll
  for (int mf = 0; mf < 4; ++mf) {
#pragma unroll
    for (int nf = 0; nf < 4; ++nf) {
      int col = n0 + wn * 64 + nf * 16 + lr;
      float bv = bias[col];
#pragma unroll
      for (int i = 0; i < 4; ++i) {
        int rr = m0 + wm * 64 + mf * 16 + 4 * g + i;
        of[(size_t)rr * 2048 + col] = acc[mf][nf][i] + bv;
      }
    }
  }
}

// ---------------- causal flash attention (32x32 MFMA, swapped QK^T) ----------------
// Round-15 version kept: ILP-split QK chains, tree row-max, complement pairing.
__global__ __launch_bounds__(256, 2) void attn_kernel(
    const u16* __restrict__ Q, const u16* __restrict__ K, const u16* __restrict__ Vt,
    u16* __restrict__ ctx) {
  int bh = blockIdx.x;
  int yy = blockIdx.y;
  int qt = (yy < 8) ? (15 - yy) : (yy - 8);
  int q0 = qt * 128;
  int t = threadIdx.x, lane = t & 63, w = t >> 6;
  int h = lane >> 5;
  int ql = lane & 31;
  int q0w = q0 + w * 32;
  int qg = q0w + ql;

  const u16* Qb = Q + (size_t)bh * 262144;
  const u16* Kb = K + (size_t)bh * 262144;
  const u16* Vb = Vt + (size_t)bh * 262144;  // [128 dk][2048 n]

  __shared__ __align__(16) u16 SM[32768];

  short8 qf[8];
  {
    const u16* qrow = Qb + (size_t)qg * 128 + 8 * h;
#pragma unroll
    for (int kk = 0; kk < 8; ++kk) qf[kk] = *(const short8*)(qrow + 16 * kk);
  }

  f32x16 acc[4] = {};
  float m = -1e30f, lsum = 0.f;

  int nt = (q0 + 128) >> 6;
  int wave_max = q0w + 31;

  auto STAGE = [&](int buf, int kv0) {
    u16* Ksb = SM + buf * 16384;
    u16* Vsb = Ksb + 8192;
#pragma unroll
    for (int it = 0; it < 4; ++it) {
      int p = t + 256 * it;
      int row = p >> 4;
      int c = (p & 15) ^ (row & 15);
      async_copy16(Kb + (size_t)(kv0 + row) * 128 + c * 8, (void*)(Ksb + p * 8));
      async_copy16(Vb + (size_t)(2 * row + (c >> 3)) * 2048 + kv0 + (c & 7) * 8,
                   (void*)(Vsb + p * 8));
    }
  };

  STAGE(0, 0);
  __syncthreads();

  for (int step = 0; step < nt; ++step) {
    int kv0 = step << 6;
    int cur = step & 1;
    if (step + 1 < nt) STAGE(cur ^ 1, (step + 1) << 6);

    if (kv0 <= wave_max) {
      const u16* Ksb = SM + cur * 16384;
      const u16* Vsb = Ksb + 8192;

      f32x16 s0 = {}, s1 = {};
      {
        f32x16 s0b = {}, s1b = {};
        __builtin_amdgcn_s_setprio(1);
#pragma unroll
        for (int kk = 0; kk < 8; kk += 2) {
          int ca = (2 * kk + h) ^ (ql & 15);
          int cbx = (2 * (kk + 1) + h) ^ (ql & 15);
          short8 kfa0 = *(const short8*)&Ksb[ql * 128 + ca * 8];
          s0 = __builtin_amdgcn_mfma_f32_32x32x16_bf16(kfa0, qf[kk], s0, 0, 0, 0);
          short8 kfa1 = *(const short8*)&Ksb[(32 + ql) * 128 + ca * 8];
          s1 = __builtin_amdgcn_mfma_f32_32x32x16_bf16(kfa1, qf[kk], s1, 0, 0, 0);
          short8 kfb0 = *(const short8*)&Ksb[ql * 128 + cbx * 8];
          s0b = __builtin_amdgcn_mfma_f32_32x32x16_bf16(kfb0, qf[kk + 1], s0b, 0, 0, 0);
          short8 kfb1 = *(const short8*)&Ksb[(32 + ql) * 128 + cbx * 8];
          s1b = __builtin_amdgcn_mfma_f32_32x32x16_bf16(kfb1, qf[kk + 1], s1b, 0, 0, 0);
        }
        __builtin_amdgcn_s_setprio(0);
#pragma unroll
        for (int r = 0; r < 16; ++r) { s0[r] += s0b[r]; s1[r] += s1b[r]; }
      }

      if (kv0 + 63 > q0w) {
#pragma unroll
        for (int r = 0; r < 16; ++r) {
          int slot = (r & 3) + 8 * (r >> 2) + 4 * h;
          if (kv0 + slot > qg) s0[r] = -1e30f;
          if (kv0 + 32 + slot > qg) s1[r] = -1e30f;
        }
      }

      float mx[16];
#pragma unroll
      for (int r = 0; r < 16; ++r) mx[r] = fmaxf(s0[r], s1[r]);
#pragma unroll
      for (int off = 8; off >= 1; off >>= 1)
#pragma unroll
        for (int r = 0; r < 8; ++r)
          if (r < off) mx[r] = fmaxf(mx[r], mx[r + off]);
      float tm = fmaxf(mx[0], __shfl_xor(mx[0], 32));
      tm *= QK_SCALE;

      if (__any(tm > m + 8.0f)) {
        float mn = fmaxf(m, tm);
        float rr = exp2f(m - mn);
        m = mn;
        lsum *= rr;
#pragma unroll
        for (int d = 0; d < 4; ++d)
#pragma unroll
          for (int i = 0; i < 16; ++i) acc[d][i] *= rr;
      }

      float rs = 0.f;
#pragma unroll
      for (int r = 0; r < 16; ++r) {
        s0[r] = exp2f(fmaf(s0[r], QK_SCALE, -m));
        s1[r] = exp2f(fmaf(s1[r], QK_SCALE, -m));
        rs += s0[r] + s1[r];
      }
      rs += __shfl_xor(rs, 32);
      lsum += rs;

      u32 up0[8], up1[8];
#pragma unroll
      for (int mi = 0; mi < 8; ++mi) {
        asm("v_cvt_pk_bf16_f32 %0, %1, %2" : "=v"(up0[mi]) : "v"(s0[2 * mi]), "v"(s0[2 * mi + 1]));
        asm("v_cvt_pk_bf16_f32 %0, %1, %2" : "=v"(up1[mi]) : "v"(s1[2 * mi]), "v"(s1[2 * mi + 1]));
      }

#pragma unroll
      for (int g16 = 0; g16 < 4; ++g16) {
        int Qd = g16 & 1;
        u32 c0 = (g16 < 2) ? up0[4 * Qd + 0] : up1[4 * Qd + 0];
        u32 c1 = (g16 < 2) ? up0[4 * Qd + 1] : up1[4 * Qd + 1];
        u32 c2 = (g16 < 2) ? up0[4 * Qd + 2] : up1[4 * Qd + 2];
        u32 c3 = (g16 < 2) ? up0[4 * Qd + 3] : up1[4 * Qd + 3];
        u32 d0 = __shfl_xor(c0, 32), d1 = __shfl_xor(c1, 32);
        u32 d2 = __shfl_xor(c2, 32), d3 = __shfl_xor(c3, 32);
        u32x4 paw;
        paw[0] = h ? d2 : c0;
        paw[1] = h ? d3 : c1;
        paw[2] = h ? c2 : d0;
        paw[3] = h ? c3 : d1;
        short8 pa = __builtin_bit_cast(short8, paw);
        __builtin_amdgcn_s_setprio(1);
#pragma unroll
        for (int d = 0; d < 4; ++d) {
          int dk = 32 * d + ql;
          int prow = dk >> 1;
          int lch = (dk & 1) * 8 + 2 * g16 + h;
          int slot = lch ^ (prow & 15);
          short8 vf = *(const short8*)&Vsb[prow * 128 + slot * 8];
          acc[d] = __builtin_amdgcn_mfma_f32_32x32x16_bf16(vf, pa, acc[d], 0, 0, 0);
        }
        __builtin_amdgcn_s_setprio(0);
      }
    }
    __syncthreads();
  }

  u16* Ot = SM + w * 4352;
  float inv = 1.f / lsum;
#pragma unroll
  for (int d = 0; d < 4; ++d)
#pragma unroll
    for (int r = 0; r < 16; ++r) {
      int dk = 32 * d + (r & 3) + 8 * (r >> 2) + 4 * h;
      Ot[ql * 136 + dk] = f2bf(acc[d][r] * inv);
    }
  __syncthreads();
  int b = bh >> 4, hh = bh & 15;
#pragma unroll
  for (int it = 0; it < 8; ++it) {
    int p = lane + 64 * it;
    int row = p >> 4, ch = p & 15;
    short8 v = *(const short8*)&Ot[row * 136 + ch * 8];
    *(short8*)(ctx + ((size_t)(b * 2048 + q0 + w * 32 + row)) * 2048 + hh * 128 + ch * 8) = v;
  }
}

// ---------------- launcher ----------------
extern "C" void kernel_launch(void* const* d_in, const int* in_sizes, int n_in,
                              void* d_out, int out_size, void* d_ws, size_t ws_size,
                              hipStream_t stream) {
  const float* x = (const float*)d_in[0];
  const float* Wq = (const float*)d_in[1];
  const float* bq = (const float*)d_in[2];
  const float* Wk = (const float*)d_in[3];
  const float* bk = (const float*)d_in[4];
  const float* Wv = (const float*)d_in[5];
  const float* bv = (const float*)d_in[6];
  const float* Wo = (const float*)d_in[7];
  const float* bo = (const float*)d_in[8];
  float* out = (float*)d_out;

  u16* xb = (u16*)d_ws;               // 4096x2048 bf16
  u16* WTq = xb + 8388608;            // WTq|WTk|WTv contiguous -> fused N=6144
  u16* WTk = WTq + 4194304;
  u16* WTv = WTk + 4194304;
  u16* WTo = WTv + 4194304;
  u16* Qs = WTo + 4194304;            // (b,h,n,dk)
  u16* Ks = Qs + 8388608;
  u16* Vt = Ks + 8388608;             // (b,h,dk,n)  <- written transposed by gemm192
  u16* ctx = Vt + 8388608;            // (b,n,d)

  cast_x_kernel<<<4096, 256, 0, stream>>>(x, xb, 8388608);
  transW_kernel<<<dim3(32, 32, 4), 256, 0, stream>>>(Wq, Wk, Wv, Wo, WTq, WTk, WTv, WTo);
  gemm192_kernel<<<dim3(32, 16), 512, 0, stream>>>(xb, WTq, bq, bk, bv, Qs, Ks, Vt);
  attn_kernel<<<dim3(32, 16), 256, 0, stream>>>(Qs, Ks, Vt, ctx);
  gemmO_kernel<<<dim3(8, 32), 512, 0, stream>>>(ctx, WTo, bo, out);
}

// Round 17
// 225.344 us; speedup vs baseline: 1.0091x; 1.0091x over previous
//
#include <hip/hip_runtime.h>

typedef unsigned short u16;
typedef unsigned int u32;
typedef __attribute__((ext_vector_type(8))) short short8;
typedef __attribute__((ext_vector_type(4))) float f32x4;
typedef __attribute__((ext_vector_type(16))) float f32x16;
typedef __attribute__((ext_vector_type(4))) u16 u16x4;
typedef __attribute__((ext_vector_type(4))) u32 u32x4;

#define QK_SCALE 0.12751736915185197f  // log2(e)/sqrt(128)

__device__ __forceinline__ u16 f2bf(float f) {
  u32 u = __builtin_bit_cast(u32, f);
  u = u + 0x7FFFu + ((u >> 16) & 1u);
  return (u16)(u >> 16);
}

__device__ __forceinline__ void async_copy16(const void* g, void* l) {
  __builtin_amdgcn_global_load_lds(
      (const __attribute__((address_space(1))) u32*)g,
      (__attribute__((address_space(3))) u32*)l, 16, 0, 0);
}

#define VMCNT(n) asm volatile("s_waitcnt vmcnt(" #n ")" ::: "memory")

// -------- fused prep: z<4 -> transpose+cast W quadrant; z==4 -> cast x --------
__global__ __launch_bounds__(256) void prep_kernel(
    const float* __restrict__ x, u16* __restrict__ xb,
    const float* __restrict__ W0, const float* __restrict__ W1,
    const float* __restrict__ W2, const float* __restrict__ W3,
    u16* __restrict__ O0, u16* __restrict__ O1, u16* __restrict__ O2, u16* __restrict__ O3) {
  int t = threadIdx.x;
  if (blockIdx.z == 4) {
    int id = blockIdx.y * 32 + blockIdx.x;  // 1024 blocks
    int base = (id * 256 + t) * 8;
#pragma unroll
    for (int it = 0; it < 4; ++it) {
      int i = base + it * 2097152;
      float4 a = *(const float4*)(x + i);
      float4 b = *(const float4*)(x + i + 4);
      short8 o;
      o[0] = (short)f2bf(a.x); o[1] = (short)f2bf(a.y);
      o[2] = (short)f2bf(a.z); o[3] = (short)f2bf(a.w);
      o[4] = (short)f2bf(b.x); o[5] = (short)f2bf(b.y);
      o[6] = (short)f2bf(b.z); o[7] = (short)f2bf(b.w);
      *(short8*)(xb + i) = o;
    }
    return;
  }
  const float* Ws[4] = {W0, W1, W2, W3};
  u16* Os[4] = {O0, O1, O2, O3};
  const float* W = Ws[blockIdx.z];
  u16* O = Os[blockIdx.z];

  __shared__ float T[64][65];
  int k0 = blockIdx.y * 64, n0 = blockIdx.x * 64;
  int r = t >> 4, c = (t & 15) * 4;
#pragma unroll
  for (int i = 0; i < 4; ++i) {
    float4 v = *(const float4*)&W[(size_t)(k0 + r + i * 16) * 2048 + n0 + c];
    T[r + i * 16][c + 0] = v.x; T[r + i * 16][c + 1] = v.y;
    T[r + i * 16][c + 2] = v.z; T[r + i * 16][c + 3] = v.w;
  }
  __syncthreads();
#pragma unroll
  for (int i = 0; i < 4; ++i) {
    int nn = r + i * 16;
    u16x4 o;
    o[0] = f2bf(T[c + 0][nn]); o[1] = f2bf(T[c + 1][nn]);
    o[2] = f2bf(T[c + 2][nn]); o[3] = f2bf(T[c + 3][nn]);
    *(u16x4*)&O[(size_t)(n0 + nn) * 2048 + k0 + c] = o;
  }
}

// ============ 256x192 merged 2-phase GEMM (QKV): BK=64, 8 waves 2Mx4N ==========
// Round-15 variant (measured best: 103.4us, MfmaUtil 44.8%).
__global__ __launch_bounds__(512, 2) void gemm192_kernel(
    const u16* __restrict__ A, const u16* __restrict__ W,
    const float* __restrict__ b0, const float* __restrict__ b1, const float* __restrict__ b2,
    u16* __restrict__ oq, u16* __restrict__ ok, u16* __restrict__ ovt) {
  __shared__ __align__(16) u16 SM[57344];  // 112 KB

  int t = threadIdx.x;
  int lane = t & 63, w = t >> 6;
  int wm = w >> 2, wn = w & 3;
  int g = lane >> 4, lr = lane & 15;
  int m0 = blockIdx.y * 256, n0 = blockIdx.x * 192;

  const u16* AsrcB = A + (size_t)(m0 + (t >> 3)) * 2048 + ((t & 7) ^ ((t >> 3) & 7)) * 8;
  const u16* BsrcB = W + (size_t)(n0 + (t >> 3)) * 2048 + ((t & 7) ^ ((t >> 3) & 7)) * 8;
  int t8 = t * 8;

  int ko0 = (g ^ (lr & 7)) * 8;
  int ko1 = ((4 + g) ^ (lr & 7)) * 8;
  int aoff[8], boff[3];
#pragma unroll
  for (int mf = 0; mf < 8; ++mf) aoff[mf] = (wm * 128 + mf * 16 + lr) * 64;
#pragma unroll
  for (int nf = 0; nf < 3; ++nf) boff[nf] = 16384 + (wn * 48 + nf * 16 + lr) * 64;

  f32x4 acc[8][3] = {};
  short8 bfr[3][2];

#define SA(bb, j, tl) \
  async_copy16(AsrcB + (size_t)(j) * 131072 + (tl) * 64, (void*)(SM + (bb) * 28672 + (j) * 4096 + t8))
#define SB(bb, j, tl) \
  async_copy16(BsrcB + (size_t)(j) * 131072 + (tl) * 64, \
               (void*)(SM + (bb) * 28672 + 16384 + (j) * 4096 + t8))

#define PH(bufofs, half, STAGE_OPS, VM_OP)                                      \
  {                                                                             \
    const u16* Ab = SM + (bufofs);                                              \
    short8 af[4][2];                                                            \
    _Pragma("unroll") for (int mf = 0; mf < 4; ++mf) {                          \
      af[mf][0] = *(const short8*)&Ab[aoff[4 * (half) + mf] + ko0];             \
      af[mf][1] = *(const short8*)&Ab[aoff[4 * (half) + mf] + ko1];             \
    }                                                                           \
    if ((half) == 0) {                                                          \
      _Pragma("unroll") for (int nf = 0; nf < 3; ++nf) {                        \
        bfr[nf][0] = *(const short8*)&Ab[boff[nf] + ko0];                       \
        bfr[nf][1] = *(const short8*)&Ab[boff[nf] + ko1];                       \
      }                                                                         \
    }                                                                           \
    STAGE_OPS;                                                                  \
    __builtin_amdgcn_s_setprio(1);                                              \
    _Pragma("unroll") for (int kk = 0; kk < 2; ++kk)                            \
        _Pragma("unroll") for (int mf = 0; mf < 4; ++mf)                        \
            _Pragma("unroll") for (int nf = 0; nf < 3; ++nf)                    \
                acc[4 * (half) + mf][nf] = __builtin_amdgcn_mfma_f32_16x16x32_bf16(\
                    af[mf][kk], bfr[nf][kk], acc[4 * (half) + mf][nf], 0, 0, 0);\
    __builtin_amdgcn_s_setprio(0);                                              \
    VM_OP;                                                                      \
    __builtin_amdgcn_s_barrier();                                               \
  }

  SB(0, 0, 0); SB(0, 1, 0); SB(0, 2, 0);
  SA(0, 0, 0); SA(0, 1, 0); SA(0, 2, 0); SA(0, 3, 0);
  SB(1, 0, 1); SB(1, 1, 1); SB(1, 2, 1);
  SA(1, 0, 1); SA(1, 2, 1);
  VMCNT(5);
  __builtin_amdgcn_s_barrier();

  for (int i = 0; i < 16; ++i) {
    bool more = i < 15;
    int t1 = 2 * i + 1, t2 = 2 * i + 2, t3 = 2 * i + 3;
    PH(0, 0, { SA(1, 1, t1); SA(1, 3, t1); }, { VMCNT(7); });
    PH(0, 1,
       { if (more) { SB(0, 0, t2); SB(0, 1, t2); SB(0, 2, t2); SA(0, 0, t2); SA(0, 2, t2); } },
       { if (more) { VMCNT(7); } else { VMCNT(2); } });
    PH(28672, 0, { if (more) { SA(0, 1, t2); SA(0, 3, t2); } },
       { if (more) { VMCNT(7); } else { VMCNT(0); } });
    PH(28672, 1,
       { if (more) { SB(1, 0, t3); SB(1, 1, t3); SB(1, 2, t3); SA(1, 0, t3); SA(1, 2, t3); } },
       { if (more) { VMCNT(7); } });
  }
#undef PH
#undef SA
#undef SB

  bool hasV = (n0 + 191) >= 4096;
#pragma unroll
  for (int mf = 0; mf < 8; ++mf) {
#pragma unroll
    for (int nf = 0; nf < 3; ++nf) {
      int colc = wn * 48 + nf * 16 + lr;
      int col = n0 + colc;
      int z = col >> 11;
      int cc = col & 2047;
      if (z < 2) {
        float bv = (z == 0 ? b0 : b1)[cc];
        u16* outb = (z == 0) ? oq : ok;
#pragma unroll
        for (int i = 0; i < 4; ++i) {
          int rr = m0 + wm * 128 + mf * 16 + 4 * g + i;
          int b = rr >> 11, np = rr & 2047, h = cc >> 7, dk = cc & 127;
          outb[((size_t)(b * 16 + h) * 2048 + np) * 128 + dk] = f2bf(acc[mf][nf][i] + bv);
        }
      } else {
        float bv = b2[cc];
#pragma unroll
        for (int i = 0; i < 4; ++i) {
          int token = wm * 128 + mf * 16 + 4 * g + i;
          SM[colc * 264 + token] = f2bf(acc[mf][nf][i] + bv);
        }
      }
    }
  }
  if (hasV) {
    __syncthreads();
    int b = m0 >> 11;
    int npb = m0 & 2047;
#pragma unroll
    for (int it = 0; it < 12; ++it) {
      int id = t + 512 * it;
      int colc = id >> 5;
      int c8 = (id & 31) * 8;
      int col = n0 + colc;
      if (col >= 4096) {
        short8 v = *(const short8*)&SM[colc * 264 + c8];
        int vcol = col - 4096;
        int h = vcol >> 7, dk = vcol & 127;
        *(short8*)&ovt[(((size_t)(b * 16 + h) * 128 + dk) * 2048) + npb + c8] = v;
      }
    }
  }
}

// ---------------- O-proj GEMM: BM=128, BN=256, triple-buffered ----------------
__global__ __launch_bounds__(512, 2) void gemmO_kernel(
    const u16* __restrict__ A, const u16* __restrict__ W,
    const float* __restrict__ bias, float* __restrict__ of) {
  __shared__ __align__(16) u16 SM[73728];  // 144 KB

  int t = threadIdx.x;
  int lane = t & 63, w = t >> 6;
  int wm = w >> 2, wn = w & 3;
  int g = lane >> 4, lr = lane & 15;
  int m0 = blockIdx.y * 128, n0 = blockIdx.x * 256;

  int sArow = ((t >> 8) << 6) + ((t >> 3) & 31);
  int c8A = (t & 7) ^ ((t >> 3) & 7);
  const u16* Asrc = A + (size_t)(m0 + sArow) * 2048 + c8A * 8;
  int rB = t >> 3;
  int c8B = (t & 7) ^ (rB & 7);
  const u16* Bsrc = W + (size_t)(n0 + rB) * 2048 + c8B * 8;

  int ko0 = (g ^ (lr & 7)) * 8;
  int ko1 = ((4 + g) ^ (lr & 7)) * 8;
  int offA[4], offB[4];
#pragma unroll
  for (int mf = 0; mf < 4; ++mf)
    offA[mf] = (mf >> 1) * 4096 + wm * 2048 + ((mf & 1) * 16 + lr) * 64;
#pragma unroll
  for (int nf = 0; nf < 4; ++nf)
    offB[nf] = 8192 + (wn >> 1) * 8192 + ((wn & 1) * 64 + nf * 16 + lr) * 64;

  f32x4 acc[4][4] = {};

#define STG_A(sbuf, mh, kt) \
  async_copy16(Asrc + (mh) * 65536 + (kt), (void*)(SM + (sbuf) + (mh) * 4096 + t * 8))
#define STG_B(sbuf, half, kt)                                                 \
  do {                                                                        \
    async_copy16(Bsrc + (half) * 262144 + (kt),                               \
                 (void*)(SM + (sbuf) + 8192 + (half) * 8192 + t * 8));        \
    async_copy16(Bsrc + (half) * 262144 + 131072 + (kt),                      \
                 (void*)(SM + (sbuf) + 8192 + (half) * 8192 + 4096 + t * 8)); \
  } while (0)

  STG_A(0, 0, 0); STG_B(0, 0, 0);
  STG_A(0, 1, 0); STG_B(0, 1, 0);
  STG_A(24576, 0, 64); STG_B(24576, 0, 64);
  STG_A(24576, 1, 64); STG_B(24576, 1, 64);
  VMCNT(6);
  __builtin_amdgcn_s_barrier();

  u32 cb = 0, sb = 49152;
  for (int tt = 0; tt < 32; ++tt) {
    int kt2 = (tt + 2) << 6;
    bool stg = tt < 30;
    const u16* Bu = SM + cb;

    short8 af[2][2], bfr[4][2];
#pragma unroll
    for (int m2 = 0; m2 < 2; ++m2) {
      af[m2][0] = *(const short8*)&Bu[offA[m2] + ko0];
      af[m2][1] = *(const short8*)&Bu[offA[m2] + ko1];
    }
#pragma unroll
    for (int nf = 0; nf < 4; ++nf) {
      bfr[nf][0] = *(const short8*)&Bu[offB[nf] + ko0];
      bfr[nf][1] = *(const short8*)&Bu[offB[nf] + ko1];
    }
    if (stg) { STG_A(sb, 0, kt2); STG_B(sb, 0, kt2); }
    __builtin_amdgcn_s_barrier();
    __builtin_amdgcn_s_setprio(1);
#pragma unroll
    for (int kk = 0; kk < 2; ++kk)
#pragma unroll
      for (int m2 = 0; m2 < 2; ++m2)
#pragma unroll
        for (int nf = 0; nf < 4; ++nf)
          acc[m2][nf] =
              __builtin_amdgcn_mfma_f32_16x16x32_bf16(af[m2][kk], bfr[nf][kk], acc[m2][nf], 0, 0, 0);
    __builtin_amdgcn_s_setprio(0);
    __builtin_amdgcn_s_barrier();

#pragma unroll
    for (int m2 = 0; m2 < 2; ++m2) {
      af[m2][0] = *(const short8*)&Bu[offA[2 + m2] + ko0];
      af[m2][1] = *(const short8*)&Bu[offA[2 + m2] + ko1];
    }
    if (stg) { STG_A(sb, 1, kt2); STG_B(sb, 1, kt2); }
    __builtin_amdgcn_s_barrier();
    __builtin_amdgcn_s_setprio(1);
#pragma unroll
    for (int kk = 0; kk < 2; ++kk)
#pragma unroll
      for (int m2 = 0; m2 < 2; ++m2)
#pragma unroll
        for (int nf = 0; nf < 4; ++nf)
          acc[2 + m2][nf] = __builtin_amdgcn_mfma_f32_16x16x32_bf16(af[m2][kk], bfr[nf][kk],
                                                                    acc[2 + m2][nf], 0, 0, 0);
    __builtin_amdgcn_s_setprio(0);
    if (tt < 30) { VMCNT(6); } else { VMCNT(0); }
    __builtin_amdgcn_s_barrier();

    cb += 24576; if (cb == 73728) cb = 0;
    sb += 24576; if (sb == 73728) sb = 0;
  }
#undef STG_A
#undef STG_B

#pragma unroll
  for (int mf = 0; mf < 4; ++mf) {
#pragma unroll
    for (int nf = 0; nf < 4; ++nf) {
      int col = n0 + wn * 64 + nf * 16 + lr;
      float bv = bias[col];
#pragma unroll
      for (int i = 0; i < 4; ++i) {
        int rr = m0 + wm * 64 + mf * 16 + 4 * g + i;
        of[(size_t)rr * 2048 + col] = acc[mf][nf][i] + bv;
      }
    }
  }
}

// ---------------- causal flash attention (32x32 MFMA, swapped QK^T) ----------------
// Round-15 version: ILP-split QK chains, tree row-max, complement pairing.
__global__ __launch_bounds__(256, 2) void attn_kernel(
    const u16* __restrict__ Q, const u16* __restrict__ K, const u16* __restrict__ Vt,
    u16* __restrict__ ctx) {
  int bh = blockIdx.x;
  int yy = blockIdx.y;
  int qt = (yy < 8) ? (15 - yy) : (yy - 8);
  int q0 = qt * 128;
  int t = threadIdx.x, lane = t & 63, w = t >> 6;
  int h = lane >> 5;
  int ql = lane & 31;
  int q0w = q0 + w * 32;
  int qg = q0w + ql;

  const u16* Qb = Q + (size_t)bh * 262144;
  const u16* Kb = K + (size_t)bh * 262144;
  const u16* Vb = Vt + (size_t)bh * 262144;  // [128 dk][2048 n]

  __shared__ __align__(16) u16 SM[32768];

  short8 qf[8];
  {
    const u16* qrow = Qb + (size_t)qg * 128 + 8 * h;
#pragma unroll
    for (int kk = 0; kk < 8; ++kk) qf[kk] = *(const short8*)(qrow + 16 * kk);
  }

  f32x16 acc[4] = {};
  float m = -1e30f, lsum = 0.f;

  int nt = (q0 + 128) >> 6;
  int wave_max = q0w + 31;

  auto STAGE = [&](int buf, int kv0) {
    u16* Ksb = SM + buf * 16384;
    u16* Vsb = Ksb + 8192;
#pragma unroll
    for (int it = 0; it < 4; ++it) {
      int p = t + 256 * it;
      int row = p >> 4;
      int c = (p & 15) ^ (row & 15);
      async_copy16(Kb + (size_t)(kv0 + row) * 128 + c * 8, (void*)(Ksb + p * 8));
      async_copy16(Vb + (size_t)(2 * row + (c >> 3)) * 2048 + kv0 + (c & 7) * 8,
                   (void*)(Vsb + p * 8));
    }
  };

  STAGE(0, 0);
  __syncthreads();

  for (int step = 0; step < nt; ++step) {
    int kv0 = step << 6;
    int cur = step & 1;
    if (step + 1 < nt) STAGE(cur ^ 1, (step + 1) << 6);

    if (kv0 <= wave_max) {
      const u16* Ksb = SM + cur * 16384;
      const u16* Vsb = Ksb + 8192;

      f32x16 s0 = {}, s1 = {};
      {
        f32x16 s0b = {}, s1b = {};
        __builtin_amdgcn_s_setprio(1);
#pragma unroll
        for (int kk = 0; kk < 8; kk += 2) {
          int ca = (2 * kk + h) ^ (ql & 15);
          int cbx = (2 * (kk + 1) + h) ^ (ql & 15);
          short8 kfa0 = *(const short8*)&Ksb[ql * 128 + ca * 8];
          s0 = __builtin_amdgcn_mfma_f32_32x32x16_bf16(kfa0, qf[kk], s0, 0, 0, 0);
          short8 kfa1 = *(const short8*)&Ksb[(32 + ql) * 128 + ca * 8];
          s1 = __builtin_amdgcn_mfma_f32_32x32x16_bf16(kfa1, qf[kk], s1, 0, 0, 0);
          short8 kfb0 = *(const short8*)&Ksb[ql * 128 + cbx * 8];
          s0b = __builtin_amdgcn_mfma_f32_32x32x16_bf16(kfb0, qf[kk + 1], s0b, 0, 0, 0);
          short8 kfb1 = *(const short8*)&Ksb[(32 + ql) * 128 + cbx * 8];
          s1b = __builtin_amdgcn_mfma_f32_32x32x16_bf16(kfb1, qf[kk + 1], s1b, 0, 0, 0);
        }
        __builtin_amdgcn_s_setprio(0);
#pragma unroll
        for (int r = 0; r < 16; ++r) { s0[r] += s0b[r]; s1[r] += s1b[r]; }
      }

      if (kv0 + 63 > q0w) {
#pragma unroll
        for (int r = 0; r < 16; ++r) {
          int slot = (r & 3) + 8 * (r >> 2) + 4 * h;
          if (kv0 + slot > qg) s0[r] = -1e30f;
          if (kv0 + 32 + slot > qg) s1[r] = -1e30f;
        }
      }

      float mx[16];
#pragma unroll
      for (int r = 0; r < 16; ++r) mx[r] = fmaxf(s0[r], s1[r]);
#pragma unroll
      for (int off = 8; off >= 1; off >>= 1)
#pragma unroll
        for (int r = 0; r < 8; ++r)
          if (r < off) mx[r] = fmaxf(mx[r], mx[r + off]);
      float tm = fmaxf(mx[0], __shfl_xor(mx[0], 32));
      tm *= QK_SCALE;

      if (__any(tm > m + 8.0f)) {
        float mn = fmaxf(m, tm);
        float rr = exp2f(m - mn);
        m = mn;
        lsum *= rr;
#pragma unroll
        for (int d = 0; d < 4; ++d)
#pragma unroll
          for (int i = 0; i < 16; ++i) acc[d][i] *= rr;
      }

      float rs = 0.f;
#pragma unroll
      for (int r = 0; r < 16; ++r) {
        s0[r] = exp2f(fmaf(s0[r], QK_SCALE, -m));
        s1[r] = exp2f(fmaf(s1[r], QK_SCALE, -m));
        rs += s0[r] + s1[r];
      }
      rs += __shfl_xor(rs, 32);
      lsum += rs;

      u32 up0[8], up1[8];
#pragma unroll
      for (int mi = 0; mi < 8; ++mi) {
        asm("v_cvt_pk_bf16_f32 %0, %1, %2" : "=v"(up0[mi]) : "v"(s0[2 * mi]), "v"(s0[2 * mi + 1]));
        asm("v_cvt_pk_bf16_f32 %0, %1, %2" : "=v"(up1[mi]) : "v"(s1[2 * mi]), "v"(s1[2 * mi + 1]));
      }

#pragma unroll
      for (int g16 = 0; g16 < 4; ++g16) {
        int Qd = g16 & 1;
        u32 c0 = (g16 < 2) ? up0[4 * Qd + 0] : up1[4 * Qd + 0];
        u32 c1 = (g16 < 2) ? up0[4 * Qd + 1] : up1[4 * Qd + 1];
        u32 c2 = (g16 < 2) ? up0[4 * Qd + 2] : up1[4 * Qd + 2];
        u32 c3 = (g16 < 2) ? up0[4 * Qd + 3] : up1[4 * Qd + 3];
        u32 d0 = __shfl_xor(c0, 32), d1 = __shfl_xor(c1, 32);
        u32 d2 = __shfl_xor(c2, 32), d3 = __shfl_xor(c3, 32);
        u32x4 paw;
        paw[0] = h ? d2 : c0;
        paw[1] = h ? d3 : c1;
        paw[2] = h ? c2 : d0;
        paw[3] = h ? c3 : d1;
        short8 pa = __builtin_bit_cast(short8, paw);
        __builtin_amdgcn_s_setprio(1);
#pragma unroll
        for (int d = 0; d < 4; ++d) {
          int dk = 32 * d + ql;
          int prow = dk >> 1;
          int lch = (dk & 1) * 8 + 2 * g16 + h;
          int slot = lch ^ (prow & 15);
          short8 vf = *(const short8*)&Vsb[prow * 128 + slot * 8];
          acc[d] = __builtin_amdgcn_mfma_f32_32x32x16_bf16(vf, pa, acc[d], 0, 0, 0);
        }
        __builtin_amdgcn_s_setprio(0);
      }
    }
    __syncthreads();
  }

  u16* Ot = SM + w * 4352;
  float inv = 1.f / lsum;
#pragma unroll
  for (int d = 0; d < 4; ++d)
#pragma unroll
    for (int r = 0; r < 16; ++r) {
      int dk = 32 * d + (r & 3) + 8 * (r >> 2) + 4 * h;
      Ot[ql * 136 + dk] = f2bf(acc[d][r] * inv);
    }
  __syncthreads();
  int b = bh >> 4, hh = bh & 15;
#pragma unroll
  for (int it = 0; it < 8; ++it) {
    int p = lane + 64 * it;
    int row = p >> 4, ch = p & 15;
    short8 v = *(const short8*)&Ot[row * 136 + ch * 8];
    *(short8*)(ctx + ((size_t)(b * 2048 + q0 + w * 32 + row)) * 2048 + hh * 128 + ch * 8) = v;
  }
}

// ---------------- launcher ----------------
extern "C" void kernel_launch(void* const* d_in, const int* in_sizes, int n_in,
                              void* d_out, int out_size, void* d_ws, size_t ws_size,
                              hipStream_t stream) {
  const float* x = (const float*)d_in[0];
  const float* Wq = (const float*)d_in[1];
  const float* bq = (const float*)d_in[2];
  const float* Wk = (const float*)d_in[3];
  const float* bk = (const float*)d_in[4];
  const float* Wv = (const float*)d_in[5];
  const float* bv = (const float*)d_in[6];
  const float* Wo = (const float*)d_in[7];
  const float* bo = (const float*)d_in[8];
  float* out = (float*)d_out;

  u16* xb = (u16*)d_ws;               // 4096x2048 bf16
  u16* WTq = xb + 8388608;            // WTq|WTk|WTv contiguous -> fused N=6144
  u16* WTk = WTq + 4194304;
  u16* WTv = WTk + 4194304;
  u16* WTo = WTv + 4194304;
  u16* Qs = WTo + 4194304;            // (b,h,n,dk)
  u16* Ks = Qs + 8388608;
  u16* Vt = Ks + 8388608;             // (b,h,dk,n)  <- written transposed by gemm192
  u16* ctx = Vt + 8388608;            // (b,n,d)

  prep_kernel<<<dim3(32, 32, 5), 256, 0, stream>>>(x, xb, Wq, Wk, Wv, Wo, WTq, WTk, WTv, WTo);
  gemm192_kernel<<<dim3(32, 16), 512, 0, stream>>>(xb, WTq, bq, bk, bv, Qs, Ks, Vt);
  attn_kernel<<<dim3(32, 16), 256, 0, stream>>>(Qs, Ks, Vt, ctx);
  gemmO_kernel<<<dim3(8, 32), 512, 0, stream>>>(ctx, WTo, bo, out);
}

// Round 18
// 217.138 us; speedup vs baseline: 1.0472x; 1.0378x over previous
//
#include <hip/hip_runtime.h>

typedef unsigned short u16;
typedef unsigned int u32;
typedef __attribute__((ext_vector_type(8))) short short8;
typedef __attribute__((ext_vector_type(4))) float f32x4;
typedef __attribute__((ext_vector_type(16))) float f32x16;
typedef __attribute__((ext_vector_type(4))) u16 u16x4;
typedef __attribute__((ext_vector_type(4))) u32 u32x4;

#define QK_SCALE 0.12751736915185197f  // log2(e)/sqrt(128)
#define EXP2(x) __builtin_amdgcn_exp2f(x)

__device__ __forceinline__ u16 f2bf(float f) {
  u32 u = __builtin_bit_cast(u32, f);
  u = u + 0x7FFFu + ((u >> 16) & 1u);
  return (u16)(u >> 16);
}

__device__ __forceinline__ void async_copy16(const void* g, void* l) {
  __builtin_amdgcn_global_load_lds(
      (const __attribute__((address_space(1))) u32*)g,
      (__attribute__((address_space(3))) u32*)l, 16, 0, 0);
}

#define VMCNT(n) asm volatile("s_waitcnt vmcnt(" #n ")" ::: "memory")

// -------- fused prep: z<4 -> transpose+cast W quadrant; z==4 -> cast x --------
__global__ __launch_bounds__(256) void prep_kernel(
    const float* __restrict__ x, u16* __restrict__ xb,
    const float* __restrict__ W0, const float* __restrict__ W1,
    const float* __restrict__ W2, const float* __restrict__ W3,
    u16* __restrict__ O0, u16* __restrict__ O1, u16* __restrict__ O2, u16* __restrict__ O3) {
  int t = threadIdx.x;
  if (blockIdx.z == 4) {
    int id = blockIdx.y * 32 + blockIdx.x;  // 1024 blocks
    int base = (id * 256 + t) * 8;
#pragma unroll
    for (int it = 0; it < 4; ++it) {
      int i = base + it * 2097152;
      float4 a = *(const float4*)(x + i);
      float4 b = *(const float4*)(x + i + 4);
      short8 o;
      o[0] = (short)f2bf(a.x); o[1] = (short)f2bf(a.y);
      o[2] = (short)f2bf(a.z); o[3] = (short)f2bf(a.w);
      o[4] = (short)f2bf(b.x); o[5] = (short)f2bf(b.y);
      o[6] = (short)f2bf(b.z); o[7] = (short)f2bf(b.w);
      *(short8*)(xb + i) = o;
    }
    return;
  }
  const float* Ws[4] = {W0, W1, W2, W3};
  u16* Os[4] = {O0, O1, O2, O3};
  const float* W = Ws[blockIdx.z];
  u16* O = Os[blockIdx.z];

  __shared__ float T[64][65];
  int k0 = blockIdx.y * 64, n0 = blockIdx.x * 64;
  int r = t >> 4, c = (t & 15) * 4;
#pragma unroll
  for (int i = 0; i < 4; ++i) {
    float4 v = *(const float4*)&W[(size_t)(k0 + r + i * 16) * 2048 + n0 + c];
    T[r + i * 16][c + 0] = v.x; T[r + i * 16][c + 1] = v.y;
    T[r + i * 16][c + 2] = v.z; T[r + i * 16][c + 3] = v.w;
  }
  __syncthreads();
#pragma unroll
  for (int i = 0; i < 4; ++i) {
    int nn = r + i * 16;
    u16x4 o;
    o[0] = f2bf(T[c + 0][nn]); o[1] = f2bf(T[c + 1][nn]);
    o[2] = f2bf(T[c + 2][nn]); o[3] = f2bf(T[c + 3][nn]);
    *(u16x4*)&O[(size_t)(n0 + nn) * 2048 + k0 + c] = o;
  }
}

// ============ 256x192 merged 2-phase GEMM (QKV): BK=64, 8 waves 2Mx4N ==========
__global__ __launch_bounds__(512, 2) void gemm192_kernel(
    const u16* __restrict__ A, const u16* __restrict__ W,
    const float* __restrict__ b0, const float* __restrict__ b1, const float* __restrict__ b2,
    u16* __restrict__ oq, u16* __restrict__ ok, u16* __restrict__ ovt) {
  __shared__ __align__(16) u16 SM[57344];  // 112 KB

  int t = threadIdx.x;
  int lane = t & 63, w = t >> 6;
  int wm = w >> 2, wn = w & 3;
  int g = lane >> 4, lr = lane & 15;
  int m0 = blockIdx.y * 256, n0 = blockIdx.x * 192;

  const u16* AsrcB = A + (size_t)(m0 + (t >> 3)) * 2048 + ((t & 7) ^ ((t >> 3) & 7)) * 8;
  const u16* BsrcB = W + (size_t)(n0 + (t >> 3)) * 2048 + ((t & 7) ^ ((t >> 3) & 7)) * 8;
  int t8 = t * 8;

  int ko0 = (g ^ (lr & 7)) * 8;
  int ko1 = ((4 + g) ^ (lr & 7)) * 8;
  int aoff[8], boff[3];
#pragma unroll
  for (int mf = 0; mf < 8; ++mf) aoff[mf] = (wm * 128 + mf * 16 + lr) * 64;
#pragma unroll
  for (int nf = 0; nf < 3; ++nf) boff[nf] = 16384 + (wn * 48 + nf * 16 + lr) * 64;

  f32x4 acc[8][3] = {};
  short8 bfr[3][2];

#define SA(bb, j, tl) \
  async_copy16(AsrcB + (size_t)(j) * 131072 + (tl) * 64, (void*)(SM + (bb) * 28672 + (j) * 4096 + t8))
#define SB(bb, j, tl) \
  async_copy16(BsrcB + (size_t)(j) * 131072 + (tl) * 64, \
               (void*)(SM + (bb) * 28672 + 16384 + (j) * 4096 + t8))

#define PH(bufofs, half, STAGE_OPS, VM_OP)                                      \
  {                                                                             \
    const u16* Ab = SM + (bufofs);                                              \
    short8 af[4][2];                                                            \
    _Pragma("unroll") for (int mf = 0; mf < 4; ++mf) {                          \
      af[mf][0] = *(const short8*)&Ab[aoff[4 * (half) + mf] + ko0];             \
      af[mf][1] = *(const short8*)&Ab[aoff[4 * (half) + mf] + ko1];             \
    }                                                                           \
    if ((half) == 0) {                                                          \
      _Pragma("unroll") for (int nf = 0; nf < 3; ++nf) {                        \
        bfr[nf][0] = *(const short8*)&Ab[boff[nf] + ko0];                       \
        bfr[nf][1] = *(const short8*)&Ab[boff[nf] + ko1];                       \
      }                                                                         \
    }                                                                           \
    STAGE_OPS;                                                                  \
    __builtin_amdgcn_s_setprio(1);                                              \
    _Pragma("unroll") for (int kk = 0; kk < 2; ++kk)                            \
        _Pragma("unroll") for (int mf = 0; mf < 4; ++mf)                        \
            _Pragma("unroll") for (int nf = 0; nf < 3; ++nf)                    \
                acc[4 * (half) + mf][nf] = __builtin_amdgcn_mfma_f32_16x16x32_bf16(\
                    af[mf][kk], bfr[nf][kk], acc[4 * (half) + mf][nf], 0, 0, 0);\
    __builtin_amdgcn_s_setprio(0);                                              \
    VM_OP;                                                                      \
    __builtin_amdgcn_s_barrier();                                               \
  }

  SB(0, 0, 0); SB(0, 1, 0); SB(0, 2, 0);
  SA(0, 0, 0); SA(0, 1, 0); SA(0, 2, 0); SA(0, 3, 0);
  SB(1, 0, 1); SB(1, 1, 1); SB(1, 2, 1);
  SA(1, 0, 1); SA(1, 2, 1);
  VMCNT(5);
  __builtin_amdgcn_s_barrier();

  for (int i = 0; i < 16; ++i) {
    bool more = i < 15;
    int t1 = 2 * i + 1, t2 = 2 * i + 2, t3 = 2 * i + 3;
    PH(0, 0, { SA(1, 1, t1); SA(1, 3, t1); }, { VMCNT(7); });
    PH(0, 1,
       { if (more) { SB(0, 0, t2); SB(0, 1, t2); SB(0, 2, t2); SA(0, 0, t2); SA(0, 2, t2); } },
       { if (more) { VMCNT(7); } else { VMCNT(2); } });
    PH(28672, 0, { if (more) { SA(0, 1, t2); SA(0, 3, t2); } },
       { if (more) { VMCNT(7); } else { VMCNT(0); } });
    PH(28672, 1,
       { if (more) { SB(1, 0, t3); SB(1, 1, t3); SB(1, 2, t3); SA(1, 0, t3); SA(1, 2, t3); } },
       { if (more) { VMCNT(7); } });
  }
#undef PH
#undef SA
#undef SB

  bool hasV = (n0 + 191) >= 4096;
#pragma unroll
  for (int mf = 0; mf < 8; ++mf) {
#pragma unroll
    for (int nf = 0; nf < 3; ++nf) {
      int colc = wn * 48 + nf * 16 + lr;
      int col = n0 + colc;
      int z = col >> 11;
      int cc = col & 2047;
      if (z < 2) {
        float bv = (z == 0 ? b0 : b1)[cc];
        u16* outb = (z == 0) ? oq : ok;
#pragma unroll
        for (int i = 0; i < 4; ++i) {
          int rr = m0 + wm * 128 + mf * 16 + 4 * g + i;
          int b = rr >> 11, np = rr & 2047, h = cc >> 7, dk = cc & 127;
          outb[((size_t)(b * 16 + h) * 2048 + np) * 128 + dk] = f2bf(acc[mf][nf][i] + bv);
        }
      } else {
        float bv = b2[cc];
#pragma unroll
        for (int i = 0; i < 4; ++i) {
          int token = wm * 128 + mf * 16 + 4 * g + i;
          SM[colc * 264 + token] = f2bf(acc[mf][nf][i] + bv);
        }
      }
    }
  }
  if (hasV) {
    __syncthreads();
    int b = m0 >> 11;
    int npb = m0 & 2047;
#pragma unroll
    for (int it = 0; it < 12; ++it) {
      int id = t + 512 * it;
      int colc = id >> 5;
      int c8 = (id & 31) * 8;
      int col = n0 + colc;
      if (col >= 4096) {
        short8 v = *(const short8*)&SM[colc * 264 + c8];
        int vcol = col - 4096;
        int h = vcol >> 7, dk = vcol & 127;
        *(short8*)&ovt[(((size_t)(b * 16 + h) * 128 + dk) * 2048) + npb + c8] = v;
      }
    }
  }
}

// ---------------- O-proj GEMM: BM=128, BN=256, triple-buffered ----------------
__global__ __launch_bounds__(512, 2) void gemmO_kernel(
    const u16* __restrict__ A, const u16* __restrict__ W,
    const float* __restrict__ bias, float* __restrict__ of) {
  __shared__ __align__(16) u16 SM[73728];  // 144 KB

  int t = threadIdx.x;
  int lane = t & 63, w = t >> 6;
  int wm = w >> 2, wn = w & 3;
  int g = lane >> 4, lr = lane & 15;
  int m0 = blockIdx.y * 128, n0 = blockIdx.x * 256;

  int sArow = ((t >> 8) << 6) + ((t >> 3) & 31);
  int c8A = (t & 7) ^ ((t >> 3) & 7);
  const u16* Asrc = A + (size_t)(m0 + sArow) * 2048 + c8A * 8;
  int rB = t >> 3;
  int c8B = (t & 7) ^ (rB & 7);
  const u16* Bsrc = W + (size_t)(n0 + rB) * 2048 + c8B * 8;

  int ko0 = (g ^ (lr & 7)) * 8;
  int ko1 = ((4 + g) ^ (lr & 7)) * 8;
  int offA[4], offB[4];
#pragma unroll
  for (int mf = 0; mf < 4; ++mf)
    offA[mf] = (mf >> 1) * 4096 + wm * 2048 + ((mf & 1) * 16 + lr) * 64;
#pragma unroll
  for (int nf = 0; nf < 4; ++nf)
    offB[nf] = 8192 + (wn >> 1) * 8192 + ((wn & 1) * 64 + nf * 16 + lr) * 64;

  f32x4 acc[4][4] = {};

#define STG_A(sbuf, mh, kt) \
  async_copy16(Asrc + (mh) * 65536 + (kt), (void*)(SM + (sbuf) + (mh) * 4096 + t * 8))
#define STG_B(sbuf, half, kt)                                                 \
  do {                                                                        \
    async_copy16(Bsrc + (half) * 262144 + (kt),                               \
                 (void*)(SM + (sbuf) + 8192 + (half) * 8192 + t * 8));        \
    async_copy16(Bsrc + (half) * 262144 + 131072 + (kt),                      \
                 (void*)(SM + (sbuf) + 8192 + (half) * 8192 + 4096 + t * 8)); \
  } while (0)

  STG_A(0, 0, 0); STG_B(0, 0, 0);
  STG_A(0, 1, 0); STG_B(0, 1, 0);
  STG_A(24576, 0, 64); STG_B(24576, 0, 64);
  STG_A(24576, 1, 64); STG_B(24576, 1, 64);
  VMCNT(6);
  __builtin_amdgcn_s_barrier();

  u32 cb = 0, sb = 49152;
  for (int tt = 0; tt < 32; ++tt) {
    int kt2 = (tt + 2) << 6;
    bool stg = tt < 30;
    const u16* Bu = SM + cb;

    short8 af[2][2], bfr[4][2];
#pragma unroll
    for (int m2 = 0; m2 < 2; ++m2) {
      af[m2][0] = *(const short8*)&Bu[offA[m2] + ko0];
      af[m2][1] = *(const short8*)&Bu[offA[m2] + ko1];
    }
#pragma unroll
    for (int nf = 0; nf < 4; ++nf) {
      bfr[nf][0] = *(const short8*)&Bu[offB[nf] + ko0];
      bfr[nf][1] = *(const short8*)&Bu[offB[nf] + ko1];
    }
    if (stg) { STG_A(sb, 0, kt2); STG_B(sb, 0, kt2); }
    __builtin_amdgcn_s_barrier();
    __builtin_amdgcn_s_setprio(1);
#pragma unroll
    for (int kk = 0; kk < 2; ++kk)
#pragma unroll
      for (int m2 = 0; m2 < 2; ++m2)
#pragma unroll
        for (int nf = 0; nf < 4; ++nf)
          acc[m2][nf] =
              __builtin_amdgcn_mfma_f32_16x16x32_bf16(af[m2][kk], bfr[nf][kk], acc[m2][nf], 0, 0, 0);
    __builtin_amdgcn_s_setprio(0);
    __builtin_amdgcn_s_barrier();

#pragma unroll
    for (int m2 = 0; m2 < 2; ++m2) {
      af[m2][0] = *(const short8*)&Bu[offA[2 + m2] + ko0];
      af[m2][1] = *(const short8*)&Bu[offA[2 + m2] + ko1];
    }
    if (stg) { STG_A(sb, 1, kt2); STG_B(sb, 1, kt2); }
    __builtin_amdgcn_s_barrier();
    __builtin_amdgcn_s_setprio(1);
#pragma unroll
    for (int kk = 0; kk < 2; ++kk)
#pragma unroll
      for (int m2 = 0; m2 < 2; ++m2)
#pragma unroll
        for (int nf = 0; nf < 4; ++nf)
          acc[2 + m2][nf] = __builtin_amdgcn_mfma_f32_16x16x32_bf16(af[m2][kk], bfr[nf][kk],
                                                                    acc[2 + m2][nf], 0, 0, 0);
    __builtin_amdgcn_s_setprio(0);
    if (tt < 30) { VMCNT(6); } else { VMCNT(0); }
    __builtin_amdgcn_s_barrier();

    cb += 24576; if (cb == 73728) cb = 0;
    sb += 24576; if (sb == 73728) sb = 0;
  }
#undef STG_A
#undef STG_B

#pragma unroll
  for (int mf = 0; mf < 4; ++mf) {
#pragma unroll
    for (int nf = 0; nf < 4; ++nf) {
      int col = n0 + wn * 64 + nf * 16 + lr;
      float bv = bias[col];
#pragma unroll
      for (int i = 0; i < 4; ++i) {
        int rr = m0 + wm * 64 + mf * 16 + 4 * g + i;
        of[(size_t)rr * 2048 + col] = acc[mf][nf][i] + bv;
      }
    }
  }
}

// ---------------- causal flash attention (32x32 MFMA, swapped QK^T) ----------------
// Round-18: raw v_exp_f32 (EXP2 builtin) + depth-5 row-sum tree; rest = round 17.
__global__ __launch_bounds__(256, 2) void attn_kernel(
    const u16* __restrict__ Q, const u16* __restrict__ K, const u16* __restrict__ Vt,
    u16* __restrict__ ctx) {
  int bh = blockIdx.x;
  int yy = blockIdx.y;
  int qt = (yy < 8) ? (15 - yy) : (yy - 8);
  int q0 = qt * 128;
  int t = threadIdx.x, lane = t & 63, w = t >> 6;
  int h = lane >> 5;
  int ql = lane & 31;
  int q0w = q0 + w * 32;
  int qg = q0w + ql;

  const u16* Qb = Q + (size_t)bh * 262144;
  const u16* Kb = K + (size_t)bh * 262144;
  const u16* Vb = Vt + (size_t)bh * 262144;  // [128 dk][2048 n]

  __shared__ __align__(16) u16 SM[32768];

  short8 qf[8];
  {
    const u16* qrow = Qb + (size_t)qg * 128 + 8 * h;
#pragma unroll
    for (int kk = 0; kk < 8; ++kk) qf[kk] = *(const short8*)(qrow + 16 * kk);
  }

  f32x16 acc[4] = {};
  float m = -1e30f, lsum = 0.f;

  int nt = (q0 + 128) >> 6;
  int wave_max = q0w + 31;

  auto STAGE = [&](int buf, int kv0) {
    u16* Ksb = SM + buf * 16384;
    u16* Vsb = Ksb + 8192;
#pragma unroll
    for (int it = 0; it < 4; ++it) {
      int p = t + 256 * it;
      int row = p >> 4;
      int c = (p & 15) ^ (row & 15);
      async_copy16(Kb + (size_t)(kv0 + row) * 128 + c * 8, (void*)(Ksb + p * 8));
      async_copy16(Vb + (size_t)(2 * row + (c >> 3)) * 2048 + kv0 + (c & 7) * 8,
                   (void*)(Vsb + p * 8));
    }
  };

  STAGE(0, 0);
  __syncthreads();

  for (int step = 0; step < nt; ++step) {
    int kv0 = step << 6;
    int cur = step & 1;
    if (step + 1 < nt) STAGE(cur ^ 1, (step + 1) << 6);

    if (kv0 <= wave_max) {
      const u16* Ksb = SM + cur * 16384;
      const u16* Vsb = Ksb + 8192;

      f32x16 s0 = {}, s1 = {};
      {
        f32x16 s0b = {}, s1b = {};
        __builtin_amdgcn_s_setprio(1);
#pragma unroll
        for (int kk = 0; kk < 8; kk += 2) {
          int ca = (2 * kk + h) ^ (ql & 15);
          int cbx = (2 * (kk + 1) + h) ^ (ql & 15);
          short8 kfa0 = *(const short8*)&Ksb[ql * 128 + ca * 8];
          s0 = __builtin_amdgcn_mfma_f32_32x32x16_bf16(kfa0, qf[kk], s0, 0, 0, 0);
          short8 kfa1 = *(const short8*)&Ksb[(32 + ql) * 128 + ca * 8];
          s1 = __builtin_amdgcn_mfma_f32_32x32x16_bf16(kfa1, qf[kk], s1, 0, 0, 0);
          short8 kfb0 = *(const short8*)&Ksb[ql * 128 + cbx * 8];
          s0b = __builtin_amdgcn_mfma_f32_32x32x16_bf16(kfb0, qf[kk + 1], s0b, 0, 0, 0);
          short8 kfb1 = *(const short8*)&Ksb[(32 + ql) * 128 + cbx * 8];
          s1b = __builtin_amdgcn_mfma_f32_32x32x16_bf16(kfb1, qf[kk + 1], s1b, 0, 0, 0);
        }
        __builtin_amdgcn_s_setprio(0);
#pragma unroll
        for (int r = 0; r < 16; ++r) { s0[r] += s0b[r]; s1[r] += s1b[r]; }
      }

      if (kv0 + 63 > q0w) {
#pragma unroll
        for (int r = 0; r < 16; ++r) {
          int slot = (r & 3) + 8 * (r >> 2) + 4 * h;
          if (kv0 + slot > qg) s0[r] = -1e30f;
          if (kv0 + 32 + slot > qg) s1[r] = -1e30f;
        }
      }

      float mx[16];
#pragma unroll
      for (int r = 0; r < 16; ++r) mx[r] = fmaxf(s0[r], s1[r]);
#pragma unroll
      for (int off = 8; off >= 1; off >>= 1)
#pragma unroll
        for (int r = 0; r < 8; ++r)
          if (r < off) mx[r] = fmaxf(mx[r], mx[r + off]);
      float tm = fmaxf(mx[0], __shfl_xor(mx[0], 32));
      tm *= QK_SCALE;

      if (__any(tm > m + 8.0f)) {
        float mn = fmaxf(m, tm);
        float rr = EXP2(m - mn);
        m = mn;
        lsum *= rr;
#pragma unroll
        for (int d = 0; d < 4; ++d)
#pragma unroll
          for (int i = 0; i < 16; ++i) acc[d][i] *= rr;
      }

      // p = exp2(s*scale - m); row-sum via depth-5 tree
      float ps[16];
#pragma unroll
      for (int r = 0; r < 16; ++r) {
        s0[r] = EXP2(fmaf(s0[r], QK_SCALE, -m));
        s1[r] = EXP2(fmaf(s1[r], QK_SCALE, -m));
        ps[r] = s0[r] + s1[r];
      }
#pragma unroll
      for (int off = 8; off >= 1; off >>= 1)
#pragma unroll
        for (int r = 0; r < 8; ++r)
          if (r < off) ps[r] += ps[r + off];
      float rs = ps[0];
      rs += __shfl_xor(rs, 32);
      lsum += rs;

      u32 up0[8], up1[8];
#pragma unroll
      for (int mi = 0; mi < 8; ++mi) {
        asm("v_cvt_pk_bf16_f32 %0, %1, %2" : "=v"(up0[mi]) : "v"(s0[2 * mi]), "v"(s0[2 * mi + 1]));
        asm("v_cvt_pk_bf16_f32 %0, %1, %2" : "=v"(up1[mi]) : "v"(s1[2 * mi]), "v"(s1[2 * mi + 1]));
      }

#pragma unroll
      for (int g16 = 0; g16 < 4; ++g16) {
        int Qd = g16 & 1;
        u32 c0 = (g16 < 2) ? up0[4 * Qd + 0] : up1[4 * Qd + 0];
        u32 c1 = (g16 < 2) ? up0[4 * Qd + 1] : up1[4 * Qd + 1];
        u32 c2 = (g16 < 2) ? up0[4 * Qd + 2] : up1[4 * Qd + 2];
        u32 c3 = (g16 < 2) ? up0[4 * Qd + 3] : up1[4 * Qd + 3];
        u32 d0 = __shfl_xor(c0, 32), d1 = __shfl_xor(c1, 32);
        u32 d2 = __shfl_xor(c2, 32), d3 = __shfl_xor(c3, 32);
        u32x4 paw;
        paw[0] = h ? d2 : c0;
        paw[1] = h ? d3 : c1;
        paw[2] = h ? c2 : d0;
        paw[3] = h ? c3 : d1;
        short8 pa = __builtin_bit_cast(short8, paw);
        __builtin_amdgcn_s_setprio(1);
#pragma unroll
        for (int d = 0; d < 4; ++d) {
          int dk = 32 * d + ql;
          int prow = dk >> 1;
          int lch = (dk & 1) * 8 + 2 * g16 + h;
          int slot = lch ^ (prow & 15);
          short8 vf = *(const short8*)&Vsb[prow * 128 + slot * 8];
          acc[d] = __builtin_amdgcn_mfma_f32_32x32x16_bf16(vf, pa, acc[d], 0, 0, 0);
        }
        __builtin_amdgcn_s_setprio(0);
      }
    }
    __syncthreads();
  }

  u16* Ot = SM + w * 4352;
  float inv = 1.f / lsum;
#pragma unroll
  for (int d = 0; d < 4; ++d)
#pragma unroll
    for (int r = 0; r < 16; ++r) {
      int dk = 32 * d + (r & 3) + 8 * (r >> 2) + 4 * h;
      Ot[ql * 136 + dk] = f2bf(acc[d][r] * inv);
    }
  __syncthreads();
  int b = bh >> 4, hh = bh & 15;
#pragma unroll
  for (int it = 0; it < 8; ++it) {
    int p = lane + 64 * it;
    int row = p >> 4, ch = p & 15;
    short8 v = *(const short8*)&Ot[row * 136 + ch * 8];
    *(short8*)(ctx + ((size_t)(b * 2048 + q0 + w * 32 + row)) * 2048 + hh * 128 + ch * 8) = v;
  }
}

// ---------------- launcher ----------------
extern "C" void kernel_launch(void* const* d_in, const int* in_sizes, int n_in,
                              void* d_out, int out_size, void* d_ws, size_t ws_size,
                              hipStream_t stream) {
  const float* x = (const float*)d_in[0];
  const float* Wq = (const float*)d_in[1];
  const float* bq = (const float*)d_in[2];
  const float* Wk = (const float*)d_in[3];
  const float* bk = (const float*)d_in[4];
  const float* Wv = (const float*)d_in[5];
  const float* bv = (const float*)d_in[6];
  const float* Wo = (const float*)d_in[7];
  const float* bo = (const float*)d_in[8];
  float* out = (float*)d_out;

  u16* xb = (u16*)d_ws;               // 4096x2048 bf16
  u16* WTq = xb + 8388608;            // WTq|WTk|WTv contiguous -> fused N=6144
  u16* WTk = WTq + 4194304;
  u16* WTv = WTk + 4194304;
  u16* WTo = WTv + 4194304;
  u16* Qs = WTo + 4194304;            // (b,h,n,dk)
  u16* Ks = Qs + 8388608;
  u16* Vt = Ks + 8388608;             // (b,h,dk,n)
  u16* ctx = Vt + 8388608;            // (b,n,d)

  prep_kernel<<<dim3(32, 32, 5), 256, 0, stream>>>(x, xb, Wq, Wk, Wv, Wo, WTq, WTk, WTv, WTo);
  gemm192_kernel<<<dim3(32, 16), 512, 0, stream>>>(xb, WTq, bq, bk, bv, Qs, Ks, Vt);
  attn_kernel<<<dim3(32, 16), 256, 0, stream>>>(Qs, Ks, Vt, ctx);
  gemmO_kernel<<<dim3(8, 32), 512, 0, stream>>>(ctx, WTo, bo, out);
}